// Round 1
// baseline (163.364 us; speedup 1.0000x reference)
//
#include <hip/hip_runtime.h>
#include <math.h>

#define SIGMA_BOOST 2.0f
#define EPSILON 1e-6f

// ---------------------------------------------------------------------------
// Pre-pass: per-t parameters -> float4 {mean_row, mean_col, sigma, pvalue}
//   mean  = sigmoid(pmean) * (N-1)
//   sigma = (softplus(psigma + SIGMA_BOOST) + EPS) * N
// softplus via stable logaddexp(x,0) = max(x,0) + log1p(exp(-|x|)) to match
// numpy's formulation. Plain expf/log1pf (accurate, ~1 ulp) to minimize
// round-boundary index flips vs the reference.
// ---------------------------------------------------------------------------
__global__ void params_kernel(const float2* __restrict__ pmeans,
                              const float* __restrict__ psigmas,
                              const float* __restrict__ pvalues,
                              float4* __restrict__ params, int N) {
    int t = blockIdx.x * blockDim.x + threadIdx.x;
    if (t >= N) return;
    float2 pm = pmeans[t];
    float scale = (float)(N - 1);
    float m0 = __fmul_rn(__fdiv_rn(1.0f, __fadd_rn(1.0f, expf(-pm.x))), scale);
    float m1 = __fmul_rn(__fdiv_rn(1.0f, __fadd_rn(1.0f, expf(-pm.y))), scale);
    float z  = __fadd_rn(psigmas[t], SIGMA_BOOST);
    float sp = __fadd_rn(fmaxf(z, 0.0f), log1pf(expf(-fabsf(z))));
    float sg = __fmul_rn(__fadd_rn(sp, EPSILON), (float)N);
    params[t] = make_float4(m0, m1, sg, pvalues[t]);
}

// ---------------------------------------------------------------------------
// One block per batch row b. 64 KB LDS accumulator holds the whole y-row:
// scatter-adds hit LDS atomics (ds_add_f32; random addrs ~2-way = free),
// final write-out is coalesced float4. No global atomics, no memset pass.
// INLINE_PARAMS: fallback path when ws is too small for the param table.
// ---------------------------------------------------------------------------
template <bool INLINE_PARAMS>
__launch_bounds__(1024, 1)
__global__ void contract_kernel(const float* __restrict__ x,
                                const float2* __restrict__ noise,
                                const float4* __restrict__ params,
                                const float2* __restrict__ pmeans,
                                const float* __restrict__ psigmas,
                                const float* __restrict__ pvalues,
                                float* __restrict__ y, int N) {
    extern __shared__ float ly[];
    const int b = blockIdx.x;
    const int tid = threadIdx.x;
    const int nthr = blockDim.x;

    // zero LDS accumulator (vectorized)
    float4* ly4 = (float4*)ly;
    const int n4 = N >> 2;
    for (int i = tid; i < n4; i += nthr) ly4[i] = make_float4(0.f, 0.f, 0.f, 0.f);
    __syncthreads();

    const float*  xb = x + (size_t)b * N;
    const float2* nb = noise + (size_t)b * N;
    const float fN1 = (float)(N - 1);

    for (int t = tid; t < N; t += nthr) {
        float m0, m1, sg, pv;
        if (INLINE_PARAMS) {
            float2 pm = pmeans[t];
            float scale = (float)(N - 1);
            m0 = __fmul_rn(__fdiv_rn(1.0f, __fadd_rn(1.0f, expf(-pm.x))), scale);
            m1 = __fmul_rn(__fdiv_rn(1.0f, __fadd_rn(1.0f, expf(-pm.y))), scale);
            float z  = __fadd_rn(psigmas[t], SIGMA_BOOST);
            float sp = __fadd_rn(fmaxf(z, 0.0f), log1pf(expf(-fabsf(z))));
            sg = __fmul_rn(__fadd_rn(sp, EPSILON), (float)N);
            pv = pvalues[t];
        } else {
            float4 p = params[t];
            m0 = p.x; m1 = p.y; sg = p.z; pv = p.w;
        }
        float2 nz = nb[t];
        // sample = mean + sigma*noise, deliberately UNFUSED to match numpy's
        // separate mul+add rounding (fma would shift round-half boundaries).
        float s0 = __fadd_rn(m0, __fmul_rn(sg, nz.x));
        float s1 = __fadd_rn(m1, __fmul_rn(sg, nz.y));
        // np.round = half-to-even = rintf; clamp in float, then exact int cvt
        int row = (int)fminf(fmaxf(rintf(s0), 0.0f), fN1);
        int col = (int)fminf(fmaxf(rintf(s1), 0.0f), fN1);
        float contrib = __fmul_rn(pv, xb[col]);
        atomicAdd(&ly[row], contrib);
    }
    __syncthreads();

    // coalesced write-out of the full row
    float4* yb4 = (float4*)(y + (size_t)b * N);
    for (int i = tid; i < n4; i += nthr) yb4[i] = ly4[i];
}

extern "C" void kernel_launch(void* const* d_in, const int* in_sizes, int n_in,
                              void* d_out, int out_size, void* d_ws, size_t ws_size,
                              hipStream_t stream) {
    const float*  x       = (const float*)d_in[0];
    const float2* noise   = (const float2*)d_in[1];
    const float2* pmeans  = (const float2*)d_in[2];
    const float*  psigmas = (const float*)d_in[3];
    const float*  pvalues = (const float*)d_in[4];
    float* y = (float*)d_out;

    const int N = in_sizes[3];          // psigmas is (N,)
    const int B = in_sizes[0] / N;      // x is (B,N)

    const size_t params_bytes = (size_t)N * sizeof(float4);
    const bool use_ws = (ws_size >= params_bytes) && (d_ws != nullptr);

    const int block = 1024;
    const size_t lds_bytes = (size_t)N * sizeof(float);  // 64 KB at N=16384

    if (use_ws) {
        float4* params = (float4*)d_ws;
        params_kernel<<<(N + 255) / 256, 256, 0, stream>>>(pmeans, psigmas,
                                                           pvalues, params, N);
        contract_kernel<false><<<B, block, lds_bytes, stream>>>(
            x, noise, params, nullptr, nullptr, nullptr, y, N);
    } else {
        contract_kernel<true><<<B, block, lds_bytes, stream>>>(
            x, noise, nullptr, pmeans, psigmas, pvalues, y, N);
    }
}